// Round 2
// baseline (197.982 us; speedup 1.0000x reference)
//
#include <hip/hip_runtime.h>

#define NGRAPHS 1024
#define NNODES  65536
#define CHUNK   32   // nodes per block: 2048 blocks, perfectly balanced

// Exclusive prefix sum of counts -> offs[0..NGRAPHS] (offs[NGRAPHS] = NNODES).
__global__ __launch_bounds__(1024) void scan_kernel(const int* __restrict__ counts,
                                                    int* __restrict__ offs) {
    __shared__ int s[NGRAPHS];
    const int t = threadIdx.x;
    const int v = counts[t];
    s[t] = v;
    __syncthreads();
    for (int d = 1; d < NGRAPHS; d <<= 1) {
        int x = (t >= d) ? s[t - d] : 0;
        __syncthreads();
        if (t >= d) s[t] += x;
        __syncthreads();
    }
    offs[t] = s[t] - v;                       // exclusive start
    if (t == NGRAPHS - 1) offs[NGRAPHS] = s[t];
}

// Node-balanced pooling: block b owns nodes [b*CHUNK, (b+1)*CHUNK).
// Thread t streams the float4 at flat offset t of each 1024-float node row
// (fully coalesced). Per same-graph run, accumulate in registers; at a run
// boundary, flush partial*(1/cnt) with atomicAdd into the permuted layout:
//   input-flat i = 4t+j  (p = i>>8, d = i&255)  ->  out o = d*4 + p
//                                               = 16*(t&63) + 4*j + (t>>6)
__global__ __launch_bounds__(256) void pool_kernel(const float4* __restrict__ f4,
                                                   const int* __restrict__ offs,
                                                   float* __restrict__ out) {
    const int t = threadIdx.x;
    int node = blockIdx.x * CHUNK;
    const int end = node + CHUNK;             // NNODES % CHUNK == 0

    // binary search: largest g with offs[g] <= node  (uniform across block)
    int lo = 0, hi = NGRAPHS - 1;
    while (lo < hi) {
        int mid = (lo + hi + 1) >> 1;
        if (offs[mid] <= node) lo = mid; else hi = mid - 1;
    }
    int g = lo;

    const int obase = ((t & 63) << 4) | (t >> 6);
    const float4* p = f4 + (size_t)node * 256 + t;

    while (node < end) {
        const int seg_start = offs[g];
        const int seg_end   = offs[g + 1];
        const int run_end   = min(end, seg_end);

        float ax = 0.f, ay = 0.f, az = 0.f, aw = 0.f;
        float bx = 0.f, by = 0.f, bz = 0.f, bw = 0.f;
        for (; node + 2 <= run_end; node += 2) {
            float4 v0 = p[0];
            float4 v1 = p[256];
            p += 512;
            ax += v0.x; ay += v0.y; az += v0.z; aw += v0.w;
            bx += v1.x; by += v1.y; bz += v1.z; bw += v1.w;
        }
        if (node < run_end) {
            float4 v0 = p[0];
            p += 256;
            ax += v0.x; ay += v0.y; az += v0.z; aw += v0.w;
            ++node;
        }

        const float inv = 1.0f / (float)(seg_end - seg_start);
        float* og = out + (size_t)g * 1024 + obase;
        atomicAdd(og + 0,  (ax + bx) * inv);
        atomicAdd(og + 4,  (ay + by) * inv);
        atomicAdd(og + 8,  (az + bz) * inv);
        atomicAdd(og + 12, (aw + bw) * inv);
        ++g;
    }
}

extern "C" void kernel_launch(void* const* d_in, const int* in_sizes, int n_in,
                              void* d_out, int out_size, void* d_ws, size_t ws_size,
                              hipStream_t stream) {
    const float* features = (const float*)d_in[0];
    const int* counts = (const int*)d_in[1];
    int* offs = (int*)d_ws;                   // 1025 ints of scratch

    hipMemsetAsync(d_out, 0, (size_t)out_size * sizeof(float), stream);
    scan_kernel<<<1, 1024, 0, stream>>>(counts, offs);
    pool_kernel<<<NNODES / CHUNK, 256, 0, stream>>>((const float4*)features, offs,
                                                    (float*)d_out);
}

// Round 3
// 59.580 us; speedup vs baseline: 3.3230x; 3.3230x over previous
//
#include <hip/hip_runtime.h>

#define NGRAPHS 1024

// Exclusive prefix sum of counts -> per-graph start offsets.
__global__ __launch_bounds__(1024) void scan_kernel(const int* __restrict__ counts,
                                                    int* __restrict__ offs) {
    __shared__ int s[NGRAPHS];
    const int t = threadIdx.x;
    const int v = counts[t];
    s[t] = v;
    __syncthreads();
    for (int d = 1; d < NGRAPHS; d <<= 1) {
        int x = (t >= d) ? s[t - d] : 0;
        __syncthreads();
        if (t >= d) s[t] += x;
        __syncthreads();
    }
    offs[t] = s[t] - v;  // exclusive start
}

// One block (512 threads = 8 waves) per graph.
//   col = t & 255 : which float4 of the 1024-float node row (coalesced)
//   nr  = t >> 8  : node-row parity (2-way node parallelism)
// Main loop: 8 independent float4 loads in flight per wave (covers 16 nodes
// per iteration) -> ~160 GB/s per block, so the largest segment (~440 nodes,
// 1.8 MB) drains in ~11 us instead of R0's ~88 us.
__global__ __launch_bounds__(512, 8) void pool_kernel(const float4* __restrict__ f4,
                                                      const int* __restrict__ counts,
                                                      const int* __restrict__ offs,
                                                      float4* __restrict__ out4) {
    const int g = blockIdx.x;
    const int t = threadIdx.x;
    const int col = t & 255;
    const int nr = t >> 8;
    const int start = offs[g];
    const int cnt = counts[g];

    const float4* base = f4 + (size_t)start * 256 + col;

    float ax0 = 0.f, ay0 = 0.f, az0 = 0.f, aw0 = 0.f;
    float ax1 = 0.f, ay1 = 0.f, az1 = 0.f, aw1 = 0.f;

    int n = 0;
    for (; n + 16 <= cnt; n += 16) {
        const float4* q = base + (size_t)(n + nr) * 256;
        float4 v0 = q[0];
        float4 v1 = q[512];
        float4 v2 = q[1024];
        float4 v3 = q[1536];
        float4 v4 = q[2048];
        float4 v5 = q[2560];
        float4 v6 = q[3072];
        float4 v7 = q[3584];
        ax0 += v0.x; ay0 += v0.y; az0 += v0.z; aw0 += v0.w;
        ax1 += v1.x; ay1 += v1.y; az1 += v1.z; aw1 += v1.w;
        ax0 += v2.x; ay0 += v2.y; az0 += v2.z; aw0 += v2.w;
        ax1 += v3.x; ay1 += v3.y; az1 += v3.z; aw1 += v3.w;
        ax0 += v4.x; ay0 += v4.y; az0 += v4.z; aw0 += v4.w;
        ax1 += v5.x; ay1 += v5.y; az1 += v5.z; aw1 += v5.w;
        ax0 += v6.x; ay0 += v6.y; az0 += v6.z; aw0 += v6.w;
        ax1 += v7.x; ay1 += v7.y; az1 += v7.z; aw1 += v7.w;
    }
    if (n < cnt) {
        // Clamped, unconditional loads keep 8 in flight through the tail.
        const int last = cnt - 1;
        #pragma unroll
        for (int k = 0; k < 8; ++k) {
            const int idx = n + nr + 2 * k;
            const float4 v = base[(size_t)min(idx, last) * 256];
            const float w = (idx < cnt) ? 1.0f : 0.0f;
            ax0 += v.x * w; ay0 += v.y * w; az0 += v.z * w; aw0 += v.w * w;
        }
    }

    __shared__ float4 part[512];   // 8 KiB
    __shared__ float trans[1024];  // 4 KiB
    float4 a;
    a.x = ax0 + ax1; a.y = ay0 + ay1; a.z = az0 + az1; a.w = aw0 + aw1;
    part[t] = a;
    __syncthreads();

    if (t < 256) {
        const float inv = 1.0f / (float)cnt;
        float4 s0 = part[t];
        float4 s1 = part[t + 256];
        float4 m;
        m.x = (s0.x + s1.x) * inv;
        m.y = (s0.y + s1.y) * inv;
        m.z = (s0.z + s1.z) * inv;
        m.w = (s0.w + s1.w) * inv;
        reinterpret_cast<float4*>(trans)[t] = m;  // trans[i] = mean at input-flat i
    }
    __syncthreads();

    if (t < 256) {
        // out o = 4t+j -> d = t, p = j -> value = trans[j*256 + t]
        float4 o;
        o.x = trans[t];
        o.y = trans[256 + t];
        o.z = trans[512 + t];
        o.w = trans[768 + t];
        out4[(size_t)g * 256 + t] = o;
    }
}

extern "C" void kernel_launch(void* const* d_in, const int* in_sizes, int n_in,
                              void* d_out, int out_size, void* d_ws, size_t ws_size,
                              hipStream_t stream) {
    const float* features = (const float*)d_in[0];
    const int* counts = (const int*)d_in[1];
    int* offs = (int*)d_ws;  // 1024 ints of scratch

    scan_kernel<<<1, 1024, 0, stream>>>(counts, offs);
    pool_kernel<<<NGRAPHS, 512, 0, stream>>>((const float4*)features, counts, offs,
                                             (float4*)d_out);
}

// Round 4
// 58.938 us; speedup vs baseline: 3.3591x; 1.0109x over previous
//
#include <hip/hip_runtime.h>

#define NGRAPHS   1024
#define NNODES    65536
#define SLOT      32      // max nodes per partial-sum slot
#define MAXSLOTS  3040    // sum ceil(c_i/32) <= (65536 + 1024*31)/32 = 3040

// One block, 1024 threads: exclusive scans of counts -> offs[0..1024]
// and of ceil(counts/SLOT) -> slot_offs[0..1024]. Two-level shfl scan.
__global__ __launch_bounds__(1024) void scan_kernel(const int* __restrict__ counts,
                                                    int* __restrict__ offs,
                                                    int* __restrict__ slot_offs) {
    const int t = threadIdx.x;
    const int lane = t & 63, w = t >> 6;  // 16 waves
    const int c = counts[t];
    const int s = (c + SLOT - 1) >> 5;

    int ci = c, si = s;  // inclusive in-wave scan
    #pragma unroll
    for (int d = 1; d < 64; d <<= 1) {
        int cc = __shfl_up(ci, d);
        int ss = __shfl_up(si, d);
        if (lane >= d) { ci += cc; si += ss; }
    }
    __shared__ int cw[16], sw[16];
    if (lane == 63) { cw[w] = ci; sw[w] = si; }
    __syncthreads();
    int cbase = 0, sbase = 0;
    for (int i = 0; i < w; ++i) { cbase += cw[i]; sbase += sw[i]; }

    offs[t] = cbase + ci - c;            // exclusive
    slot_offs[t] = sbase + si - s;
    if (t == 1023) {
        offs[NGRAPHS] = cbase + ci;       // == NNODES
        slot_offs[NGRAPHS] = sbase + si;  // == total slots
    }
}

// Uniform balanced streaming: block b sums <=32 node rows (one slot) into a
// 4 KiB partial, stored coalesced to ws. Thread t owns float4 column t.
__global__ __launch_bounds__(256, 8) void partial_kernel(const float4* __restrict__ f4,
                                                         const int* __restrict__ offs,
                                                         const int* __restrict__ slot_offs,
                                                         float4* __restrict__ partials) {
    const int b = blockIdx.x;
    if (b >= slot_offs[NGRAPHS]) return;
    const int t = threadIdx.x;

    // largest g with slot_offs[g] <= b  (uniform across block)
    int lo = 0, hi = NGRAPHS - 1;
    while (lo < hi) {
        int mid = (lo + hi + 1) >> 1;
        if (slot_offs[mid] <= b) lo = mid; else hi = mid - 1;
    }
    const int g = lo;
    const int k = b - slot_offs[g];
    const int s = offs[g] + k * SLOT;
    const int len = min(s + SLOT, offs[g + 1]) - s;

    const float4* base = f4 + (size_t)s * 256 + t;
    float4 a0 = {0, 0, 0, 0}, a1 = {0, 0, 0, 0}, a2 = {0, 0, 0, 0}, a3 = {0, 0, 0, 0};

    int n = 0;
    for (; n + 8 <= len; n += 8) {
        const float4* q = base + (size_t)n * 256;
        float4 v0 = q[0],    v1 = q[256],  v2 = q[512],  v3 = q[768];
        float4 v4 = q[1024], v5 = q[1280], v6 = q[1536], v7 = q[1792];
        a0.x += v0.x; a0.y += v0.y; a0.z += v0.z; a0.w += v0.w;
        a1.x += v1.x; a1.y += v1.y; a1.z += v1.z; a1.w += v1.w;
        a2.x += v2.x; a2.y += v2.y; a2.z += v2.z; a2.w += v2.w;
        a3.x += v3.x; a3.y += v3.y; a3.z += v3.z; a3.w += v3.w;
        a0.x += v4.x; a0.y += v4.y; a0.z += v4.z; a0.w += v4.w;
        a1.x += v5.x; a1.y += v5.y; a1.z += v5.z; a1.w += v5.w;
        a2.x += v6.x; a2.y += v6.y; a2.z += v6.z; a2.w += v6.w;
        a3.x += v7.x; a3.y += v7.y; a3.z += v7.z; a3.w += v7.w;
    }
    if (n < len) {
        const int last = len - 1;
        #pragma unroll
        for (int j = 0; j < 8; ++j) {  // clamped: all 8 issued in parallel
            const int idx = n + j;
            const float4 v = base[(size_t)min(idx, last) * 256];
            const float wgt = (idx < len) ? 1.0f : 0.0f;
            a0.x += v.x * wgt; a0.y += v.y * wgt; a0.z += v.z * wgt; a0.w += v.w * wgt;
        }
    }

    float4 a;
    a.x = (a0.x + a1.x) + (a2.x + a3.x);
    a.y = (a0.y + a1.y) + (a2.y + a3.y);
    a.z = (a0.z + a1.z) + (a2.z + a3.z);
    a.w = (a0.w + a1.w) + (a2.w + a3.w);
    partials[(size_t)b * 256 + t] = a;
}

// One block per graph: gather <=14 partials, scale by 1/cnt, LDS-transpose
// input-flat i = p*256+d -> out o = d*4+p, one float4 store per thread.
__global__ __launch_bounds__(256) void combine_kernel(const float4* __restrict__ partials,
                                                      const int* __restrict__ offs,
                                                      const int* __restrict__ slot_offs,
                                                      float4* __restrict__ out4) {
    const int g = blockIdx.x;
    const int t = threadIdx.x;
    const int k0 = slot_offs[g], k1 = slot_offs[g + 1];
    const int cnt = offs[g + 1] - offs[g];

    float4 a = {0, 0, 0, 0};
    for (int k = k0; k < k1; k += 4) {
        #pragma unroll
        for (int j = 0; j < 4; ++j) {  // clamped: 4 loads in flight
            const int kk = min(k + j, k1 - 1);
            const float wgt = (k + j < k1) ? 1.0f : 0.0f;
            const float4 v = partials[(size_t)kk * 256 + t];
            a.x += v.x * wgt; a.y += v.y * wgt; a.z += v.z * wgt; a.w += v.w * wgt;
        }
    }

    const float inv = 1.0f / (float)cnt;
    __shared__ float trans[1024];
    float4 m = {a.x * inv, a.y * inv, a.z * inv, a.w * inv};
    reinterpret_cast<float4*>(trans)[t] = m;  // trans[i] = mean at input-flat i
    __syncthreads();

    float4 o;
    o.x = trans[t];
    o.y = trans[256 + t];
    o.z = trans[512 + t];
    o.w = trans[768 + t];
    out4[(size_t)g * 256 + t] = o;
}

extern "C" void kernel_launch(void* const* d_in, const int* in_sizes, int n_in,
                              void* d_out, int out_size, void* d_ws, size_t ws_size,
                              hipStream_t stream) {
    const float* features = (const float*)d_in[0];
    const int* counts = (const int*)d_in[1];

    int* offs = (int*)d_ws;                                  // 1025 ints
    int* slot_offs = offs + 1056;                            // 1025 ints (padded start)
    float4* partials = (float4*)((char*)d_ws + 16384);       // 3040 * 4 KiB = 12.2 MiB

    scan_kernel<<<1, 1024, 0, stream>>>(counts, offs, slot_offs);
    partial_kernel<<<MAXSLOTS, 256, 0, stream>>>((const float4*)features, offs,
                                                 slot_offs, partials);
    combine_kernel<<<NGRAPHS, 256, 0, stream>>>(partials, offs, slot_offs,
                                                (float4*)d_out);
}

// Round 5
// 53.923 us; speedup vs baseline: 3.6716x; 1.0930x over previous
//
#include <hip/hip_runtime.h>

#define NGRAPHS  1024
#define NNODES   65536
#define SLOT     32
#define MAXSLOTS 3040   // sum ceil(c_i/32) <= (65536 + 1024*31)/32 = 3040

// Redundant in-block scan: 256 threads, counts[1024] ->
//   s_offs[0..1024]  exclusive node offsets (s_offs[1024] = 65536)
//   s_slot[0..1024]  exclusive slot offsets (s_slot[1024] = total slots)
// ~0.5 us, L2-hot after the first blocks touch counts. Replaces the
// serialized single-block scan kernel (+~5 us on the critical path).
__device__ inline void block_scan(const int* __restrict__ counts,
                                  int* s_offs, int* s_slot) {
    const int t = threadIdx.x;
    const int lane = t & 63, w = t >> 6;  // 4 waves
    const int4 cv = reinterpret_cast<const int4*>(counts)[t];
    const int c0 = cv.x, c1 = cv.y, c2 = cv.z, c3 = cv.w;
    const int s0 = (c0 + 31) >> 5, s1 = (c1 + 31) >> 5;
    const int s2 = (c2 + 31) >> 5, s3 = (c3 + 31) >> 5;
    const int lc = c0 + c1 + c2 + c3;
    const int ls = s0 + s1 + s2 + s3;
    int ic = lc, is = ls;  // inclusive wave scan of per-thread sums
    #pragma unroll
    for (int d = 1; d < 64; d <<= 1) {
        int cc = __shfl_up(ic, d);
        int ss = __shfl_up(is, d);
        if (lane >= d) { ic += cc; is += ss; }
    }
    __shared__ int wc[4], wsl[4];
    if (lane == 63) { wc[w] = ic; wsl[w] = is; }
    __syncthreads();
    int bc = 0, bs = 0;
    for (int i = 0; i < w; ++i) { bc += wc[i]; bs += wsl[i]; }
    const int ec = bc + ic - lc;  // exclusive before this thread's 4 graphs
    const int es = bs + is - ls;
    s_offs[4 * t + 0] = ec;
    s_offs[4 * t + 1] = ec + c0;
    s_offs[4 * t + 2] = ec + c0 + c1;
    s_offs[4 * t + 3] = ec + c0 + c1 + c2;
    s_slot[4 * t + 0] = es;
    s_slot[4 * t + 1] = es + s0;
    s_slot[4 * t + 2] = es + s0 + s1;
    s_slot[4 * t + 3] = es + s0 + s1 + s2;
    if (t == 255) { s_offs[1024] = ec + lc; s_slot[1024] = es + ls; }
    __syncthreads();
}

// Block b sums slot b (<=32 node rows). Single-slot graphs (cnt<=32) are
// finished in place: scale + LDS transpose + direct d_out store. Multi-slot
// graphs store a raw 4 KiB partial; slot 0 also records desc[g]={k0,cnt}.
__global__ __launch_bounds__(256, 8) void partial_kernel(const float4* __restrict__ f4,
                                                         const int* __restrict__ counts,
                                                         int2* __restrict__ desc,
                                                         float4* __restrict__ partials,
                                                         float4* __restrict__ out4) {
    __shared__ int s_offs[1025];
    __shared__ int s_slot[1025];
    __shared__ float s_trans[1024];
    const int t = threadIdx.x;
    block_scan(counts, s_offs, s_slot);

    const int b = blockIdx.x;
    if (b >= s_slot[1024]) return;

    // largest g with s_slot[g] <= b (LDS binary search, uniform)
    int lo = 0, hi = NGRAPHS - 1;
    while (lo < hi) {
        int mid = (lo + hi + 1) >> 1;
        if (s_slot[mid] <= b) lo = mid; else hi = mid - 1;
    }
    const int g = lo;
    const int k = b - s_slot[g];
    const int gs = s_offs[g], ge = s_offs[g + 1];
    const int cnt = ge - gs;
    const int s = gs + k * SLOT;
    const int len = min(SLOT, ge - s);
    if (k == 0 && t == 0) desc[g] = make_int2(b, cnt);

    const float4* base = f4 + (size_t)s * 256 + t;
    float4 a0 = {0, 0, 0, 0}, a1 = {0, 0, 0, 0}, a2 = {0, 0, 0, 0}, a3 = {0, 0, 0, 0};

    int n = 0;
    for (; n + 8 <= len; n += 8) {
        const float4* q = base + (size_t)n * 256;
        float4 v0 = q[0],    v1 = q[256],  v2 = q[512],  v3 = q[768];
        float4 v4 = q[1024], v5 = q[1280], v6 = q[1536], v7 = q[1792];
        a0.x += v0.x; a0.y += v0.y; a0.z += v0.z; a0.w += v0.w;
        a1.x += v1.x; a1.y += v1.y; a1.z += v1.z; a1.w += v1.w;
        a2.x += v2.x; a2.y += v2.y; a2.z += v2.z; a2.w += v2.w;
        a3.x += v3.x; a3.y += v3.y; a3.z += v3.z; a3.w += v3.w;
        a0.x += v4.x; a0.y += v4.y; a0.z += v4.z; a0.w += v4.w;
        a1.x += v5.x; a1.y += v5.y; a1.z += v5.z; a1.w += v5.w;
        a2.x += v6.x; a2.y += v6.y; a2.z += v6.z; a2.w += v6.w;
        a3.x += v7.x; a3.y += v7.y; a3.z += v7.z; a3.w += v7.w;
    }
    if (n < len) {
        const int last = len - 1;
        #pragma unroll
        for (int j = 0; j < 8; ++j) {  // clamped: all 8 in flight
            const int idx = n + j;
            const float4 v = base[(size_t)min(idx, last) * 256];
            const float wgt = (idx < len) ? 1.0f : 0.0f;
            a0.x += v.x * wgt; a0.y += v.y * wgt; a0.z += v.z * wgt; a0.w += v.w * wgt;
        }
    }

    float4 a;
    a.x = (a0.x + a1.x) + (a2.x + a3.x);
    a.y = (a0.y + a1.y) + (a2.y + a3.y);
    a.z = (a0.z + a1.z) + (a2.z + a3.z);
    a.w = (a0.w + a1.w) + (a2.w + a3.w);

    if (cnt <= SLOT) {
        // whole graph in this slot: finish here (scale + transpose + store)
        const float inv = 1.0f / (float)cnt;
        float4 m = {a.x * inv, a.y * inv, a.z * inv, a.w * inv};
        reinterpret_cast<float4*>(s_trans)[t] = m;  // s_trans[i] = mean at flat i
        __syncthreads();
        float4 o;  // out o=4t+j -> value s_trans[j*256 + t]
        o.x = s_trans[t];
        o.y = s_trans[256 + t];
        o.z = s_trans[512 + t];
        o.w = s_trans[768 + t];
        out4[(size_t)g * 256 + t] = o;
    } else {
        partials[(size_t)b * 256 + t] = a;
    }
}

// One block per multi-slot graph: gather partials, scale, transpose, store.
__global__ __launch_bounds__(256) void combine_kernel(const float4* __restrict__ partials,
                                                      const int2* __restrict__ desc,
                                                      float4* __restrict__ out4) {
    const int g = blockIdx.x;
    const int2 dd = desc[g];
    const int cnt = dd.y;
    if (cnt <= SLOT) return;  // already written by partial_kernel
    const int t = threadIdx.x;
    const int k0 = dd.x;
    const int k1 = k0 + ((cnt + 31) >> 5);

    float4 a = {0, 0, 0, 0};
    for (int k = k0; k < k1; k += 4) {
        #pragma unroll
        for (int j = 0; j < 4; ++j) {  // clamped: 4 loads in flight
            const int kk = min(k + j, k1 - 1);
            const float wgt = (k + j < k1) ? 1.0f : 0.0f;
            const float4 v = partials[(size_t)kk * 256 + t];
            a.x += v.x * wgt; a.y += v.y * wgt; a.z += v.z * wgt; a.w += v.w * wgt;
        }
    }

    const float inv = 1.0f / (float)cnt;
    __shared__ float s_trans[1024];
    float4 m = {a.x * inv, a.y * inv, a.z * inv, a.w * inv};
    reinterpret_cast<float4*>(s_trans)[t] = m;
    __syncthreads();
    float4 o;
    o.x = s_trans[t];
    o.y = s_trans[256 + t];
    o.z = s_trans[512 + t];
    o.w = s_trans[768 + t];
    out4[(size_t)g * 256 + t] = o;
}

extern "C" void kernel_launch(void* const* d_in, const int* in_sizes, int n_in,
                              void* d_out, int out_size, void* d_ws, size_t ws_size,
                              hipStream_t stream) {
    const float* features = (const float*)d_in[0];
    const int* counts = (const int*)d_in[1];

    int2* desc = (int2*)d_ws;                            // 1024 * 8 B
    float4* partials = (float4*)((char*)d_ws + 16384);   // <=3040 * 4 KiB

    partial_kernel<<<MAXSLOTS, 256, 0, stream>>>((const float4*)features, counts,
                                                 desc, partials, (float4*)d_out);
    combine_kernel<<<NGRAPHS, 256, 0, stream>>>(partials, desc, (float4*)d_out);
}